// Round 6
// baseline (644.859 us; speedup 1.0000x reference)
//
#include <hip/hip_runtime.h>
#include <stdint.h>

#define N_HEADS   32
#define N_KV      8
#define HEAD_DIM  128
#define HIDDEN_DIM 4096
#define BSZ       2
#define SEQ       2048
#define TOT_HEADS 48
#define QKV_DIM   6144   // TOT_HEADS * HEAD_DIM
#define ROWS      4096   // BSZ * SEQ
#define ROPE_HEADS 40    // Q + K heads (V not rope'd)

typedef __attribute__((ext_vector_type(4)))  float f32x4;
typedef __attribute__((ext_vector_type(16))) float f32x16;
typedef __attribute__((ext_vector_type(8)))  short bf16x8;
typedef unsigned short u16;
typedef unsigned int   u32;

#define AS1 __attribute__((address_space(1)))
#define AS3 __attribute__((address_space(3)))

static __device__ __forceinline__ float bf16f(u16 u) { return __uint_as_float(((u32)u) << 16); }
static __device__ __forceinline__ u16 f2bf(float f) {
  u32 x = __float_as_uint(f);
  x += 0x7fffu + ((x >> 16) & 1u);   // round-to-nearest-even
  return (u16)(x >> 16);
}
static __device__ __forceinline__ u32 cvt_pk_bf16(float lo, float hi) {
  u32 r;
  asm("v_cvt_pk_bf16_f32 %0, %1, %2" : "=v"(r) : "v"(lo), "v"(hi));
  return r;
}
static __device__ __forceinline__ bf16x8 mk8(u32 a, u32 b, u32 c, u32 d) {
  union { u32 u[4]; bf16x8 v; } x;
  x.u[0] = a; x.u[1] = b; x.u[2] = c; x.u[3] = d;
  return x.v;
}

// ---------------- cast f32 -> bf16 (vectorized) ----------------
__global__ void cast_f32_bf16_k(const float4* __restrict__ in, ushort4* __restrict__ out, int n4) {
  int i = blockIdx.x * blockDim.x + threadIdx.x;
  const int stride = gridDim.x * blockDim.x;
  for (; i < n4; i += stride) {
    float4 v = in[i];
    ushort4 o;
    o.x = f2bf(v.x); o.y = f2bf(v.y); o.z = f2bf(v.z); o.w = f2bf(v.w);
    out[i] = o;
  }
}

// ---------------- RoPE cos/sin tables (S x 64, half-dim) ----------------
__global__ void rope_tables_k(float* __restrict__ ctab, float* __restrict__ stab) {
  int t = blockIdx.x * blockDim.x + threadIdx.x;
  if (t >= SEQ * 64) return;
  int s = t >> 6, i = t & 63;
  float inv = powf(10000.0f, -(float)i / 64.0f);
  float ang = (float)s * inv;
  float sv, cv;
  sincosf(ang, &sv, &cv);
  ctab[t] = cv; stab[t] = sv;
}

// ---------------- 256x256 deep-pipelined bf16 GEMM: C = A * B^T ----------------
// 8 waves (2M x 4N), BK=32, ring-4 K-slots per matrix (64KB+64KB LDS).
// Stage 1 half (A or B K-tile, 2 x global_load_lds) per phase, 6 phases ahead;
// vmcnt(8) gate once per tile (counted, never 0 until the tail), raw s_barrier
// (one per phase), sched_barrier pins, setprio around MFMA clusters.
// Swizzle: LDS chunk (row, pos) holds global chunk c = pos ^ ((row>>1)&3),
// applied on the pre-swizzled GLOBAL source and the ds_read (same involution).
#define VM8 asm volatile("s_waitcnt vmcnt(8)" ::: "memory")
#define VM4 asm volatile("s_waitcnt vmcnt(4)" ::: "memory")
#define VM0 asm volatile("s_waitcnt vmcnt(0)" ::: "memory")

#define PH_EVEN(t, WAITOP, DOSTAGE)                                            \
  {                                                                            \
    WAITOP;                                                                    \
    __builtin_amdgcn_sched_barrier(0);                                         \
    __builtin_amdgcn_s_barrier();                                              \
    __builtin_amdgcn_sched_barrier(0);                                         \
    if (DOSTAGE) stageA((t) + 3);                                              \
    const int slot = ((t) & 3) << 10;                                          \
    _Pragma("unroll")                                                          \
    for (int n = 0; n < 4; ++n)                                                \
      bf[n] = *reinterpret_cast<const bf16x8*>(&LB[slot + bbase + (n << 6)]);  \
    bf16x8 af[4];                                                              \
    _Pragma("unroll")                                                          \
    for (int m = 0; m < 4; ++m)                                                \
      af[m] = *reinterpret_cast<const bf16x8*>(&LA[slot + abase + (m << 6)]);  \
    __builtin_amdgcn_s_setprio(1);                                             \
    _Pragma("unroll")                                                          \
    for (int m = 0; m < 4; ++m)                                                \
      _Pragma("unroll")                                                        \
      for (int n = 0; n < 4; ++n)                                              \
        acc[m][n] = __builtin_amdgcn_mfma_f32_16x16x32_bf16(af[m], bf[n], acc[m][n], 0, 0, 0); \
    __builtin_amdgcn_s_setprio(0);                                             \
  }

#define PH_ODD(t, DOSTAGE)                                                     \
  {                                                                            \
    __builtin_amdgcn_sched_barrier(0);                                         \
    __builtin_amdgcn_s_barrier();                                              \
    __builtin_amdgcn_sched_barrier(0);                                         \
    if (DOSTAGE) stageB((t) + 3);                                              \
    const int slot = ((t) & 3) << 10;                                          \
    bf16x8 af[4];                                                              \
    _Pragma("unroll")                                                          \
    for (int m = 0; m < 4; ++m)                                                \
      af[m] = *reinterpret_cast<const bf16x8*>(&LA[slot + abase + ((4 + m) << 6)]); \
    __builtin_amdgcn_s_setprio(1);                                             \
    _Pragma("unroll")                                                          \
    for (int m = 0; m < 4; ++m)                                                \
      _Pragma("unroll")                                                        \
      for (int n = 0; n < 4; ++n)                                              \
        acc[4 + m][n] = __builtin_amdgcn_mfma_f32_16x16x32_bf16(af[m], bf[n], acc[4 + m][n], 0, 0, 0); \
    __builtin_amdgcn_s_setprio(0);                                             \
  }

template<int F32OUT>
__global__ __launch_bounds__(512, 2)
void gemm256_k(const u16* __restrict__ A, const u16* __restrict__ Bw,
               void* __restrict__ C, int M, int N, int K)
{
  __shared__ uint4 LA[4096];   // 4 slots x 1024 chunks = 64 KB
  __shared__ uint4 LB[4096];
  const int NT = K >> 5;
  const int tid = threadIdx.x;
  const int lane = tid & 63;
  const int wave = tid >> 6;
  const int nbx = N >> 8;
  const int cpx = gridDim.x >> 3;
  const int wg  = (blockIdx.x & 7) * cpx + (blockIdx.x >> 3);   // XCD swizzle (nwg%8==0)
  const int bm = (wg / nbx) << 8;
  const int bn = (wg % nbx) << 8;

  const int wm = (wave >> 2) << 7;   // 0 / 128
  const int wn = (wave & 3) << 6;    // 0,64,128,192
  const int fr = lane & 15;
  const int fq = lane >> 4;
  const int rpos = fq ^ ((fr >> 1) & 3);
  const int abase = ((wm + fr) << 2) + rpos;
  const int bbase = ((wn + fr) << 2) + rpos;

  // staging: thread g=i*512+tid covers LDS chunk g of the slot (linear dest);
  // source pre-swizzled: row = g>>2, global chunk c = (g&3)^((g>>3)&3).
  const int rA = tid >> 2;
  const int cs8 = (((tid & 3) ^ ((tid >> 3) & 3)) << 3);
  const u16* As0 = A  + (size_t)(bm + rA) * K + cs8;
  const u16* As1 = As0 + (size_t)128 * K;
  const u16* Bs0 = Bw + (size_t)(bn + rA) * K + cs8;
  const u16* Bs1 = Bs0 + (size_t)128 * K;
  const int ldsbase = wave << 6;   // wave-uniform chunk base

  f32x4 acc[8][4];
#pragma unroll
  for (int m = 0; m < 8; ++m)
#pragma unroll
    for (int n = 0; n < 4; ++n)
      acc[m][n] = {0.f, 0.f, 0.f, 0.f};

  auto stageA = [&](int t) {
    const int slot = (t & 3) << 10;
    __builtin_amdgcn_global_load_lds((const AS1 u32*)(As0 + (t << 5)),
                                     (AS3 u32*)(LA + slot + ldsbase), 16, 0, 0);
    __builtin_amdgcn_global_load_lds((const AS1 u32*)(As1 + (t << 5)),
                                     (AS3 u32*)(LA + slot + 512 + ldsbase), 16, 0, 0);
  };
  auto stageB = [&](int t) {
    const int slot = (t & 3) << 10;
    __builtin_amdgcn_global_load_lds((const AS1 u32*)(Bs0 + (t << 5)),
                                     (AS3 u32*)(LB + slot + ldsbase), 16, 0, 0);
    __builtin_amdgcn_global_load_lds((const AS1 u32*)(Bs1 + (t << 5)),
                                     (AS3 u32*)(LB + slot + 512 + ldsbase), 16, 0, 0);
  };

  // prologue: halves A0,B0,A1,B1,A2,B2 (12 loads in flight)
  stageA(0); stageB(0); stageA(1); stageB(1); stageA(2); stageB(2);

  bf16x8 bf[4];

#pragma unroll 1
  for (int t = 0; t < NT - 2; ++t) {
    const bool st = t < NT - 3;
    PH_EVEN(t, VM8, st);
    PH_ODD(t, st);
  }
  PH_EVEN(NT - 2, VM4, false);
  PH_ODD(NT - 2, false);
  PH_EVEN(NT - 1, VM0, false);
  PH_ODD(NT - 1, false);

  // epilogue: D row = bm+wm+m*16+fq*4+i, col = bn+wn+n*16+fr
  const int col0 = bn + wn + fr;
#pragma unroll
  for (int m = 0; m < 8; ++m) {
#pragma unroll
    for (int i = 0; i < 4; ++i) {
      const int row = bm + wm + (m << 4) + (fq << 2) + i;
      if (F32OUT) {
        float* rp = reinterpret_cast<float*>(C) + (size_t)row * N + col0;
#pragma unroll
        for (int n = 0; n < 4; ++n) rp[n << 4] = acc[m][n][i];
      } else {
        u16* rp = reinterpret_cast<u16*>(C) + (size_t)row * N + col0;
#pragma unroll
        for (int n = 0; n < 4; ++n) rp[n << 4] = f2bf(acc[m][n][i]);
      }
    }
  }
}

// ---------------- RoPE + scatter Q,K heads -> Q(B,H,S,D) K(B,KV,S,D) ----------------
// Q heads pre-scaled by 1/sqrt(128)*log2(e): scores leave QK^T in log2 domain.
__global__ void rope_scatter_k(const u16* __restrict__ QKV,
                               const float* __restrict__ ctab, const float* __restrict__ stab,
                               u16* __restrict__ Qo, u16* __restrict__ Ko)
{
  const int t = blockIdx.x * blockDim.x + threadIdx.x;  // ROWS*40*64 threads
  const int d = t & 63;
  const int hh = (t >> 6) % ROPE_HEADS;
  const int row = t / (64 * ROPE_HEADS);
  const int b = row >> 11, sq = row & (SEQ - 1);
  const u16* src = QKV + (size_t)row * QKV_DIM + hh * HEAD_DIM;
  const float x1 = bf16f(src[d]);
  const float x2 = bf16f(src[d + 64]);
  const float c = ctab[(sq << 6) + d], sn = stab[(sq << 6) + d];
  float y1 = x1 * c - x2 * sn;
  float y2 = x2 * c + x1 * sn;
  u16* dst;
  if (hh < N_HEADS) {
    const float SC2 = 0.1275170747f;   // (1/sqrt(128)) * log2(e)
    y1 *= SC2; y2 *= SC2;
    dst = Qo + ((size_t)(b * N_HEADS + hh) * SEQ + sq) * HEAD_DIM;
  } else {
    dst = Ko + ((size_t)(b * N_KV + (hh - N_HEADS)) * SEQ + sq) * HEAD_DIM;
  }
  dst[d] = f2bf(y1);
  dst[d + 64] = f2bf(y2);
}

// ---------------- V transpose: QKV cols [5120,6144) -> Vt[b][kv][d][s] ----------------
__global__ __launch_bounds__(256)
void vtrans_k(const u16* __restrict__ QKV, u16* __restrict__ Vt)
{
  __shared__ u16 tile[64][72];
  const int idx = blockIdx.x;           // dt(1) | st(5) | kv(3) | b(1)
  const int dt = idx & 1;
  const int st = (idx >> 1) & 31;
  const int kv = (idx >> 6) & 7;
  const int b  = idx >> 9;
  const int tid = threadIdx.x;
  const int s0 = st << 6, d0 = dt << 6;
  const int rl = tid >> 3, cc8 = (tid & 7) << 3;
#pragma unroll
  for (int p = 0; p < 2; ++p) {
    const int sl = rl + (p << 5);
    const u16* src = QKV + (size_t)(b * SEQ + s0 + sl) * QKV_DIM
                   + (N_HEADS + N_KV + kv) * HEAD_DIM + d0 + cc8;
    *reinterpret_cast<uint4*>(&tile[sl][cc8]) = *reinterpret_cast<const uint4*>(src);
  }
  __syncthreads();
#pragma unroll
  for (int p = 0; p < 2; ++p) {
    const int dl = rl + (p << 5);
    u16 tmp[8];
#pragma unroll
    for (int k2 = 0; k2 < 8; ++k2) tmp[k2] = tile[cc8 + k2][dl];
    u16* dst = Vt + ((size_t)(b * N_KV + kv) * HEAD_DIM + d0 + dl) * SEQ + s0 + cc8;
    *reinterpret_cast<uint4*>(dst) = *reinterpret_cast<const uint4*>(tmp);
  }
}

// ---------------- MFMA flash attention (causal GQA, LDS-shared K/V) ----------------
// Unchanged from round 5 (277 -> ~124 us).
__global__ __launch_bounds__(256, 2)
void attn_mfma_k(const u16* __restrict__ Q, const u16* __restrict__ K,
                 const u16* __restrict__ Vt, u16* __restrict__ Out)
{
  __shared__ uint4 Ksm[2][512];
  __shared__ uint4 Vsm[2][512];
  const int tid  = threadIdx.x;
  const int lane = tid & 63;
  const int w    = tid >> 6;
  const int idx  = blockIdx.x;                    // p(5) | b(1) | kvh(3)
  const int kvh  = idx & 7;
  const int b    = (idx >> 3) & 1;
  const int p    = idx >> 4;                      // 0..31
  const int h    = (kvh << 2) + w;

  const int ql = lane & 31;
  const int hh = lane >> 5;

  const u16* Qh = Q  + (size_t)(b * N_HEADS + h) * SEQ * HEAD_DIM;
  const u16* Kb = K  + (size_t)(b * N_KV + kvh) * SEQ * HEAD_DIM;
  const u16* Vb = Vt + (size_t)(b * N_KV + kvh) * HEAD_DIM * SEQ;

  int koff[8];
#pragma unroll
  for (int f = 0; f < 8; ++f) koff[f] = (ql << 4) + (((f << 1) + hh) ^ (ql & 15));
  int voff0[4], voff1[4];
#pragma unroll
  for (int dblk = 0; dblk < 4; ++dblk) {
    const int d = (dblk << 5) + ql;
    voff0[dblk] = (d << 2) + (hh ^ (d & 3));
    voff1[dblk] = (d << 2) + ((2 + hh) ^ (d & 3));
  }

  auto stage = [&](int buf, int ks) {
#pragma unroll
    for (int i = 0; i < 2; ++i) {
      const int base = i * 256 + w * 64;
      const int sl = base + lane;
      const int row = sl >> 4, cs = sl & 15;
      const int g = cs ^ (row & 15);
      const u16* src = Kb + (size_t)(ks + row) * HEAD_DIM + (g << 3);
      __builtin_amdgcn_global_load_lds((const AS1 u32*)src, (AS3 u32*)&Ksm[buf][base], 16, 0, 0);
    }
#pragma unroll
    for (int i = 0; i < 2; ++i) {
      const int base = i * 256 + w * 64;
      const int sl = base + lane;
      const int d = sl >> 2, cs = sl & 3;
      const int g = cs ^ (d & 3);
      const u16* src = Vb + (size_t)d * SEQ + ks + (g << 3);
      __builtin_amdgcn_global_load_lds((const AS1 u32*)src, (AS3 u32*)&Vsm[buf][base], 16, 0, 0);
    }
  };

#pragma unroll 1
  for (int pass = 0; pass < 2; ++pass) {
    const int qi = pass ? (31 - p) : (32 + p);
    const int q0 = qi << 5;

    bf16x8 qf[8];
#pragma unroll
    for (int f = 0; f < 8; ++f)
      qf[f] = *reinterpret_cast<const bf16x8*>(Qh + (size_t)(q0 + ql) * HEAD_DIM + 16 * f + 8 * hh);

    f32x16 o[4];
#pragma unroll
    for (int dblk = 0; dblk < 4; ++dblk)
#pragma unroll
      for (int r = 0; r < 16; ++r) o[dblk][r] = 0.f;
    float m2 = -1e30f, lsum = 0.f;

    __syncthreads();
    stage(0, 0);

#pragma unroll 1
    for (int s = 0; s <= qi; ++s) {
      const int cur = s & 1;
      __syncthreads();
      if (s < qi) stage(cur ^ 1, (s + 1) << 5);

      f32x16 T;
#pragma unroll
      for (int r = 0; r < 16; ++r) T[r] = 0.f;
      __builtin_amdgcn_s_setprio(1);
#pragma unroll
      for (int f = 0; f < 8; ++f) {
        const bf16x8 kf = *reinterpret_cast<const bf16x8*>(&Ksm[cur][koff[f]]);
        T = __builtin_amdgcn_mfma_f32_32x32x16_bf16(kf, qf[f], T, 0, 0, 0);
      }
      __builtin_amdgcn_s_setprio(0);

      if (s == qi) {
#pragma unroll
        for (int r = 0; r < 16; ++r) {
          const int krow = (r & 3) + ((r >> 2) << 3) + (hh << 2);
          if (krow > ql) T[r] = -1e30f;
        }
      }
      float mt = T[0];
#pragma unroll
      for (int r = 1; r < 16; ++r) mt = fmaxf(mt, T[r]);
      mt = fmaxf(mt, __shfl_xor(mt, 32));

      if (__any(mt > m2 + 8.f)) {
        const float mnew = fmaxf(m2, mt);
        const float resc = exp2f(m2 - mnew);
        lsum *= resc;
#pragma unroll
        for (int r = 0; r < 16; ++r) {
          const int qr = (r & 3) + ((r >> 2) << 3) + (hh << 2);
          const float rr = __shfl(resc, qr);
#pragma unroll
          for (int dblk = 0; dblk < 4; ++dblk) o[dblk][r] *= rr;
        }
        m2 = mnew;
      }

      float ps = 0.f;
#pragma unroll
      for (int r = 0; r < 16; ++r) { const float pv = exp2f(T[r] - m2); T[r] = pv; ps += pv; }
      ps += __shfl_xor(ps, 32);
      lsum += ps;

      u32 pk[8], sw[8];
#pragma unroll
      for (int i = 0; i < 8; ++i) {
        pk[i] = cvt_pk_bf16(T[2 * i], T[2 * i + 1]);
        sw[i] = (u32)__shfl_xor((int)pk[i], 32);
      }
      const bf16x8 a0 = hh ? mk8(sw[2], sw[3], pk[2], pk[3])
                           : mk8(pk[0], pk[1], sw[0], sw[1]);
      const bf16x8 a1 = hh ? mk8(sw[6], sw[7], pk[6], pk[7])
                           : mk8(pk[4], pk[5], sw[4], sw[5]);

      __builtin_amdgcn_s_setprio(1);
#pragma unroll
      for (int dblk = 0; dblk < 4; ++dblk) {
        const bf16x8 va = *reinterpret_cast<const bf16x8*>(&Vsm[cur][voff0[dblk]]);
        o[dblk] = __builtin_amdgcn_mfma_f32_32x32x16_bf16(a0, va, o[dblk], 0, 0, 0);
        const bf16x8 vb2 = *reinterpret_cast<const bf16x8*>(&Vsm[cur][voff1[dblk]]);
        o[dblk] = __builtin_amdgcn_mfma_f32_32x32x16_bf16(a1, vb2, o[dblk], 0, 0, 0);
      }
      __builtin_amdgcn_s_setprio(0);
    }

    u16* Ob = Out + (size_t)(b * SEQ + q0) * HIDDEN_DIM + h * HEAD_DIM + ql;
#pragma unroll
    for (int r = 0; r < 16; ++r) {
      const int qr = (r & 3) + ((r >> 2) << 3) + (hh << 2);
      const float il = 1.0f / __shfl(lsum, qr);
      u16* rp = Ob + (size_t)qr * HIDDEN_DIM;
#pragma unroll
      for (int dblk = 0; dblk < 4; ++dblk)
        rp[dblk * 32] = f2bf(o[dblk][r] * il);
    }
  }
}

// ---------------- launch ----------------
extern "C" void kernel_launch(void* const* d_in, const int* in_sizes, int n_in,
                              void* d_out, int out_size, void* d_ws, size_t ws_size,
                              hipStream_t stream)
{
  const float* hs   = (const float*)d_in[0];
  const float* wqkv = (const float*)d_in[1];
  const float* wo   = (const float*)d_in[2];
  float* out = (float*)d_out;
  char* ws = (char*)d_ws;
  size_t off = 0;
  auto alloc = [&](size_t bytes) -> void* {
    void* p = ws + off;
    off += (bytes + 255) & ~(size_t)255;
    return p;
  };
  u16* Xbf    = (u16*)alloc((size_t)ROWS * HIDDEN_DIM * 2);
  u16* Wqkvbf = (u16*)alloc((size_t)QKV_DIM * HIDDEN_DIM * 2);
  u16* Wobf   = (u16*)alloc((size_t)HIDDEN_DIM * HIDDEN_DIM * 2);
  u16* QKVbf  = (u16*)alloc((size_t)ROWS * QKV_DIM * 2);
  u16* Qbf    = (u16*)alloc((size_t)BSZ * N_HEADS * SEQ * HEAD_DIM * 2);
  u16* Kbf    = (u16*)alloc((size_t)BSZ * N_KV * SEQ * HEAD_DIM * 2);
  u16* Vtbf   = (u16*)alloc((size_t)BSZ * N_KV * SEQ * HEAD_DIM * 2);
  float* ctab = (float*)alloc((size_t)SEQ * 64 * 4);
  float* stab = (float*)alloc((size_t)SEQ * 64 * 4);
  u16* AOut   = (u16*)alloc((size_t)ROWS * HIDDEN_DIM * 2);
  if (off > ws_size) return;

  cast_f32_bf16_k<<<2048, 256, 0, stream>>>((const float4*)hs,   (ushort4*)Xbf,    ROWS * HIDDEN_DIM / 4);
  cast_f32_bf16_k<<<2048, 256, 0, stream>>>((const float4*)wqkv, (ushort4*)Wqkvbf, QKV_DIM * HIDDEN_DIM / 4);
  cast_f32_bf16_k<<<2048, 256, 0, stream>>>((const float4*)wo,   (ushort4*)Wobf,   HIDDEN_DIM * HIDDEN_DIM / 4);
  rope_tables_k<<<(SEQ * 64) / 256, 256, 0, stream>>>(ctab, stab);

  gemm256_k<0><<<(ROWS / 256) * (QKV_DIM / 256), 512, 0, stream>>>(Xbf, Wqkvbf, (void*)QKVbf,
                                                                   ROWS, QKV_DIM, HIDDEN_DIM);
  rope_scatter_k<<<ROWS * ROPE_HEADS * 64 / 256, 256, 0, stream>>>(QKVbf, ctab, stab, Qbf, Kbf);
  vtrans_k<<<BSZ * N_KV * (SEQ / 64) * (HEAD_DIM / 64), 256, 0, stream>>>(QKVbf, Vtbf);
  attn_mfma_k<<<BSZ * N_KV * 32, 256, 0, stream>>>(Qbf, Kbf, Vtbf, AOut);
  gemm256_k<1><<<(ROWS / 256) * (HIDDEN_DIM / 256), 512, 0, stream>>>(AOut, Wobf, (void*)out,
                                                                      ROWS, HIDDEN_DIM, HIDDEN_DIM);
}